// Round 4
// baseline (41.796 us; speedup 1.0000x reference)
//
#include <hip/hip_runtime.h>
#include <hip/hip_bf16.h>

typedef __attribute__((ext_vector_type(4))) float f32x4;
typedef __attribute__((ext_vector_type(8))) short bf16x8;
typedef __attribute__((ext_vector_type(4))) short bf16x4;

#define DEVFN static __device__ __forceinline__

constexpr int Mdim = 4096;
constexpr int Ndim = 512;
constexpr int Dk   = 512;
constexpr float W_S = 0.6224593312018546f;   // sigmoid(0.5)
constexpr float W_L = 1.0f - W_S;

DEVFN short f2bf(float x) {
    __hip_bfloat16 h = __float2bfloat16(x);   // RNE
    return *reinterpret_cast<short*>(&h);
}

// ============================ prepass ============================
// Writes MFMA-fragment-tiled bf16 operands into ws:
//   At: A-concat (S ++ L) tiled as [g=row/16][ks=k/32][lane]*16B,
//       lane = ((k/8)&3)*16 + (row&15)  -> GEMM reads are 1KB wave-bursts.
//   Bt: (W_S*Ws ++ W_L*Wl) same tiling over W-rows (= output cols).
//   biasf[512] f32 = W_S*bs + W_L*bl.
constexpr int A_UNITS    = (Mdim * 2 * Dk) / 8;   // 524288 16B-units
constexpr int B_UNITS    = (Ndim * 2 * Dk) / 8;   // 65536
constexpr int BIAS_UNITS = Ndim / 8;              // 64
constexpr int TOT_UNITS  = A_UNITS + B_UNITS + BIAS_UNITS;
constexpr size_t ABF_BYTES  = (size_t)Mdim * 2 * Dk * 2;   // 8 MB
constexpr size_t BBF_BYTES  = (size_t)Ndim * 2 * Dk * 2;   // 1 MB
constexpr size_t WS_NEEDED  = ABF_BYTES + BBF_BYTES + Ndim * 4;

__global__ __launch_bounds__(256)
void prepass_kernel(const float* __restrict__ S, const float* __restrict__ L,
                    const float* __restrict__ Ws, const float* __restrict__ Wl,
                    const float* __restrict__ bs, const float* __restrict__ bl,
                    short* __restrict__ At, short* __restrict__ Bt,
                    float* __restrict__ biasf)
{
    const int t = blockIdx.x * blockDim.x + threadIdx.x;
    if (t >= TOT_UNITS) return;
    if (t < A_UNITS) {
        // dest-linear: consecutive threads -> consecutive 16B units (coalesced).
        const int l  = t & 63;
        const int ks = (t >> 6) & 31;
        const int g  = t >> 11;                 // 0..255
        const int row = g * 16 + (l & 15);
        const int k0  = ks * 32 + (l >> 4) * 8; // 0..1016, 8-elem chunk
        const float* src = (k0 < Dk) ? (S + (size_t)row * Dk + k0)
                                     : (L + (size_t)row * Dk + (k0 - Dk));
        float4 v0 = *(const float4*)src;
        float4 v1 = *(const float4*)(src + 4);
        bf16x8 o = { f2bf(v0.x), f2bf(v0.y), f2bf(v0.z), f2bf(v0.w),
                     f2bf(v1.x), f2bf(v1.y), f2bf(v1.z), f2bf(v1.w) };
        *(bf16x8*)(At + (size_t)t * 8) = o;
    } else if (t < A_UNITS + B_UNITS) {
        const int u  = t - A_UNITS;
        const int l  = u & 63;
        const int ks = (u >> 6) & 31;
        const int g  = u >> 11;                 // 0..31
        const int row = g * 16 + (l & 15);      // W row = output col
        const int k0  = ks * 32 + (l >> 4) * 8;
        const bool sm = (k0 < Dk);
        const float* src = sm ? (Ws + (size_t)row * Dk + k0)
                              : (Wl + (size_t)row * Dk + (k0 - Dk));
        const float sc = sm ? W_S : W_L;
        float4 v0 = *(const float4*)src;
        float4 v1 = *(const float4*)(src + 4);
        bf16x8 o = { f2bf(v0.x*sc), f2bf(v0.y*sc), f2bf(v0.z*sc), f2bf(v0.w*sc),
                     f2bf(v1.x*sc), f2bf(v1.y*sc), f2bf(v1.z*sc), f2bf(v1.w*sc) };
        *(bf16x8*)(Bt + (size_t)u * 8) = o;
    } else {
        const int u = t - A_UNITS - B_UNITS;
        const int j = u * 8;
        float4 s0 = *(const float4*)(bs + j), s1 = *(const float4*)(bs + j + 4);
        float4 l0 = *(const float4*)(bl + j), l1 = *(const float4*)(bl + j + 4);
        float4 o0 = { W_S*s0.x + W_L*l0.x, W_S*s0.y + W_L*l0.y,
                      W_S*s0.z + W_L*l0.z, W_S*s0.w + W_L*l0.w };
        float4 o1 = { W_S*s1.x + W_L*l1.x, W_S*s1.y + W_L*l1.y,
                      W_S*s1.z + W_L*l1.z, W_S*s1.w + W_L*l1.w };
        *(float4*)(biasf + j)     = o0;
        *(float4*)(biasf + j + 4) = o1;
    }
}

// ============================ register-direct bf16 GEMM ============================
// C[4096][512] = A @ B^T + bias.  NO LDS, NO barriers.
// 256 blocks x 128 thr (2 waves). BM=64, BN=128; wave tile 64x64
// (FLOP/operand-byte = 32, 2x the 32x32-wave config). Operands read straight
// from L2 (per-XCD working set ~12MB? A 1MB panel x 4 reuse + B 1MB x8 -> L2-hot).
// Depth-3 register pipeline covers L2 latency; statically indexed (rule #20).
constexpr int NKS = (2 * Dk) / 32;   // 32 k-steps of 32

__global__ __launch_bounds__(128)
void gemm_reg_kernel(const short* __restrict__ At, const short* __restrict__ Bt,
                     const float* __restrict__ biasf, float* __restrict__ out)
{
    const int tid  = threadIdx.x;
    const int lane = tid & 63;
    const int w    = tid >> 6;           // 0..1 (N-split within block)
    const int bid  = blockIdx.x;
    const int Mtile = bid & 63;          // 64 rows;  XCD = bid%8 = Mtile%8
    const int Ntile = bid >> 6;          // 0..3 (128 cols)

    // Fragment base pointers: group g occupies 32KB (32 ks x 64 lanes x 16B).
    const char* pA[4];
    const char* pB[4];
#pragma unroll
    for (int m = 0; m < 4; ++m)
        pA[m] = (const char*)At + ((size_t)(Mtile * 4 + m) << 15) + lane * 16;
#pragma unroll
    for (int n = 0; n < 4; ++n)
        pB[n] = (const char*)Bt + ((size_t)(Ntile * 8 + w * 4 + n) << 15) + lane * 16;

    f32x4 acc[4][4];
#pragma unroll
    for (int m = 0; m < 4; ++m)
#pragma unroll
        for (int n = 0; n < 4; ++n) acc[m][n] = (f32x4)0.0f;

    bf16x8 aP[3][4], bP[3][4];

    auto loadset = [&](int s, int ks) {
#pragma unroll
        for (int m = 0; m < 4; ++m)
            aP[s][m] = *(const bf16x8*)(pA[m] + (size_t)ks * 1024);
#pragma unroll
        for (int n = 0; n < 4; ++n)
            bP[s][n] = *(const bf16x8*)(pB[n] + (size_t)ks * 1024);
    };

    loadset(0, 0);
    loadset(1, 1);
    loadset(2, 2);

#pragma unroll
    for (int ks = 0; ks < NKS; ++ks) {
        const int s = ks % 3;            // compile-time after full unroll
#pragma unroll
        for (int m = 0; m < 4; ++m)
#pragma unroll
            for (int n = 0; n < 4; ++n)
                acc[m][n] = __builtin_amdgcn_mfma_f32_16x16x32_bf16(aP[s][m], bP[s][n], acc[m][n], 0, 0, 0);
        if (ks + 3 < NKS) loadset(s, ks + 3);   // refill just-consumed set
    }

    // Epilogue: D layout col=lane&15, row=(lane>>4)*4+r (verified m89/m91).
#pragma unroll
    for (int n = 0; n < 4; ++n) {
        const int j = Ntile * 128 + w * 64 + n * 16 + (lane & 15);
        const float bias = biasf[j];
#pragma unroll
        for (int m = 0; m < 4; ++m) {
            const int i0 = Mtile * 64 + m * 16 + ((lane >> 4) << 2);
#pragma unroll
            for (int r = 0; r < 4; ++r)
                out[(size_t)(i0 + r) * Ndim + j] = acc[m][n][r] + bias;
        }
    }
}

// ==================== fallback (round-1 fused kernel, proven 17.55us) ====================
DEVFN int swz_fb(int row, int colByte) { return row * 128 + (colByte ^ ((row & 7) << 4)); }

__global__ __launch_bounds__(512, 2)
void fused_proj_kernel(const float* __restrict__ S, const float* __restrict__ L,
                       const float* __restrict__ Ws, const float* __restrict__ Wl,
                       const float* __restrict__ bs, const float* __restrict__ bl,
                       float* __restrict__ out)
{
    __shared__ char smA[2][128 * 64 * 2];
    __shared__ char smB[2][64 * 64 * 2];
    const int tid = threadIdx.x, bid = blockIdx.x;
    const int Mbase = (bid & 31) * 128, Nbase = (bid >> 5) * 64;
    const int srow = tid >> 4, scol = (tid & 15) * 4;
    const int lane = tid & 63, wid = tid >> 6, wr = wid >> 1, wc = wid & 1;

    f32x4 acc[2][2];
#pragma unroll
    for (int m = 0; m < 2; ++m)
#pragma unroll
        for (int n = 0; n < 2; ++n) acc[m][n] = (f32x4)0.0f;
    float4 av[4]; float4 bv[2];

    auto loadTiles = [&](int kt) {
        const float* sA = (kt < 8) ? S : L;
        const float* sB = (kt < 8) ? Ws : Wl;
        const int kOff = (kt & 7) * 64 + scol;
#pragma unroll
        for (int q = 0; q < 4; ++q)
            av[q] = *(const float4*)(sA + (size_t)(Mbase + q * 32 + srow) * Dk + kOff);
#pragma unroll
        for (int q = 0; q < 2; ++q)
            bv[q] = *(const float4*)(sB + (size_t)(Nbase + q * 32 + srow) * Dk + kOff);
    };
    auto writeTiles = [&](int p, float scB) {
#pragma unroll
        for (int q = 0; q < 4; ++q) {
            bf16x4 v = { f2bf(av[q].x), f2bf(av[q].y), f2bf(av[q].z), f2bf(av[q].w) };
            *(bf16x4*)(&smA[p][swz_fb(q * 32 + srow, scol * 2)]) = v;
        }
#pragma unroll
        for (int q = 0; q < 2; ++q) {
            bf16x4 v = { f2bf(bv[q].x * scB), f2bf(bv[q].y * scB),
                         f2bf(bv[q].z * scB), f2bf(bv[q].w * scB) };
            *(bf16x4*)(&smB[p][swz_fb(q * 32 + srow, scol * 2)]) = v;
        }
    };

    loadTiles(0); writeTiles(0, W_S); loadTiles(1);
    __syncthreads();
    for (int kt = 0; kt < 16; ++kt) {
        const int p = kt & 1;
#pragma unroll
        for (int kk = 0; kk < 2; ++kk) {
            bf16x8 a[2], b[2];
            const int cb = kk * 64 + (lane >> 4) * 16;
#pragma unroll
            for (int m = 0; m < 2; ++m)
                a[m] = *(const bf16x8*)(&smA[p][swz_fb(wr * 32 + m * 16 + (lane & 15), cb)]);
#pragma unroll
            for (int n = 0; n < 2; ++n)
                b[n] = *(const bf16x8*)(&smB[p][swz_fb(wc * 32 + n * 16 + (lane & 15), cb)]);
#pragma unroll
            for (int m = 0; m < 2; ++m)
#pragma unroll
                for (int n = 0; n < 2; ++n)
                    acc[m][n] = __builtin_amdgcn_mfma_f32_16x16x32_bf16(a[m], b[n], acc[m][n], 0, 0, 0);
        }
        if (kt + 1 < 16) {
            writeTiles(p ^ 1, (kt + 1 < 8) ? W_S : W_L);
            if (kt + 2 < 16) loadTiles(kt + 2);
            __syncthreads();
        }
    }
#pragma unroll
    for (int n = 0; n < 2; ++n) {
        const int j = Nbase + wc * 32 + n * 16 + (lane & 15);
        const float bias = W_S * bs[j] + W_L * bl[j];
#pragma unroll
        for (int m = 0; m < 2; ++m) {
            const int i0 = Mbase + wr * 32 + m * 16 + ((lane >> 4) << 2);
#pragma unroll
            for (int r = 0; r < 4; ++r)
                out[(size_t)(i0 + r) * Ndim + j] = acc[m][n][r] + bias;
        }
    }
}

extern "C" void kernel_launch(void* const* d_in, const int* in_sizes, int n_in,
                              void* d_out, int out_size, void* d_ws, size_t ws_size,
                              hipStream_t stream) {
    const float* S  = (const float*)d_in[0];
    const float* L  = (const float*)d_in[1];
    const float* Ws = (const float*)d_in[2];
    const float* bs = (const float*)d_in[3];
    const float* Wl = (const float*)d_in[4];
    const float* bl = (const float*)d_in[5];
    // d_in[6] = sigma: dead code in reference output.

    if (ws_size >= WS_NEEDED) {
        short* At    = (short*)d_ws;
        short* Bt    = (short*)((char*)d_ws + ABF_BYTES);
        float* biasf = (float*)((char*)d_ws + ABF_BYTES + BBF_BYTES);
        const int pre_blocks = (TOT_UNITS + 255) / 256;
        prepass_kernel<<<pre_blocks, 256, 0, stream>>>(S, L, Ws, Wl, bs, bl, At, Bt, biasf);
        gemm_reg_kernel<<<256, 128, 0, stream>>>(At, Bt, biasf, (float*)d_out);
    } else {
        fused_proj_kernel<<<256, 512, 0, stream>>>(S, L, Ws, Wl, bs, bl, (float*)d_out);
    }
}

// Round 5
// 31.780 us; speedup vs baseline: 1.3152x; 1.3152x over previous
//
#include <hip/hip_runtime.h>
#include <hip/hip_bf16.h>

typedef __attribute__((ext_vector_type(4))) float f32x4;
typedef __attribute__((ext_vector_type(8))) short bf16x8;
typedef __attribute__((ext_vector_type(4))) short bf16x4;

#define DEVFN static __device__ __forceinline__

constexpr int Mdim = 4096;
constexpr int Ndim = 512;
constexpr int Dk   = 512;
constexpr float W_S = 0.6224593312018546f;   // sigmoid(0.5)
constexpr float W_L = 1.0f - W_S;

DEVFN short f2bf(float x) {
    __hip_bfloat16 h = __float2bfloat16(x);   // RNE
    return *reinterpret_cast<short*>(&h);
}

// ============================ prepass (proven in R4) ============================
// ws: At  (S ++ L)        tiled [g=row/16][ks=k/32][lane]*16B, lane=((k/8)&3)*16+(row&15)
//     Bt  (W_S*Ws ++ W_L*Wl) same tiling (W row = output col)
//     biasf[512] f32 = W_S*bs + W_L*bl
constexpr int A_UNITS    = (Mdim * 2 * Dk) / 8;   // 524288
constexpr int B_UNITS    = (Ndim * 2 * Dk) / 8;   // 65536
constexpr int BIAS_UNITS = Ndim / 8;              // 64
constexpr int TOT_UNITS  = A_UNITS + B_UNITS + BIAS_UNITS;
constexpr size_t ABF_BYTES  = (size_t)Mdim * 2 * Dk * 2;   // 8 MB
constexpr size_t BBF_BYTES  = (size_t)Ndim * 2 * Dk * 2;   // 1 MB
constexpr size_t WS_NEEDED  = ABF_BYTES + BBF_BYTES + Ndim * 4;

__global__ __launch_bounds__(256)
void prepass_kernel(const float* __restrict__ S, const float* __restrict__ L,
                    const float* __restrict__ Ws, const float* __restrict__ Wl,
                    const float* __restrict__ bs, const float* __restrict__ bl,
                    short* __restrict__ At, short* __restrict__ Bt,
                    float* __restrict__ biasf)
{
    const int t = blockIdx.x * blockDim.x + threadIdx.x;
    if (t >= TOT_UNITS) return;
    if (t < A_UNITS) {
        const int l  = t & 63;
        const int ks = (t >> 6) & 31;
        const int g  = t >> 11;
        const int row = g * 16 + (l & 15);
        const int k0  = ks * 32 + (l >> 4) * 8;
        const float* src = (k0 < Dk) ? (S + (size_t)row * Dk + k0)
                                     : (L + (size_t)row * Dk + (k0 - Dk));
        float4 v0 = *(const float4*)src;
        float4 v1 = *(const float4*)(src + 4);
        bf16x8 o = { f2bf(v0.x), f2bf(v0.y), f2bf(v0.z), f2bf(v0.w),
                     f2bf(v1.x), f2bf(v1.y), f2bf(v1.z), f2bf(v1.w) };
        *(bf16x8*)(At + (size_t)t * 8) = o;
    } else if (t < A_UNITS + B_UNITS) {
        const int u  = t - A_UNITS;
        const int l  = u & 63;
        const int ks = (u >> 6) & 31;
        const int g  = u >> 11;
        const int row = g * 16 + (l & 15);
        const int k0  = ks * 32 + (l >> 4) * 8;
        const bool sm = (k0 < Dk);
        const float* src = sm ? (Ws + (size_t)row * Dk + k0)
                              : (Wl + (size_t)row * Dk + (k0 - Dk));
        const float sc = sm ? W_S : W_L;
        float4 v0 = *(const float4*)src;
        float4 v1 = *(const float4*)(src + 4);
        bf16x8 o = { f2bf(v0.x*sc), f2bf(v0.y*sc), f2bf(v0.z*sc), f2bf(v0.w*sc),
                     f2bf(v1.x*sc), f2bf(v1.y*sc), f2bf(v1.z*sc), f2bf(v1.w*sc) };
        *(bf16x8*)(Bt + (size_t)u * 8) = o;
    } else {
        const int u = t - A_UNITS - B_UNITS;
        const int j = u * 8;
        float4 s0 = *(const float4*)(bs + j), s1 = *(const float4*)(bs + j + 4);
        float4 l0 = *(const float4*)(bl + j), l1 = *(const float4*)(bl + j + 4);
        float4 o0 = { W_S*s0.x + W_L*l0.x, W_S*s0.y + W_L*l0.y,
                      W_S*s0.z + W_L*l0.z, W_S*s0.w + W_L*l0.w };
        float4 o1 = { W_S*s1.x + W_L*l1.x, W_S*s1.y + W_L*l1.y,
                      W_S*s1.z + W_L*l1.z, W_S*s1.w + W_L*l1.w };
        *(float4*)(biasf + j)     = o0;
        *(float4*)(biasf + j + 4) = o1;
    }
}

// ============================ reg-direct GEMM, in-block split-K ============================
// C[4096][512] = A @ B^T + bias.  BM=64, BN=128, grid 256 (1 blk/CU), 256 thr.
// 4 waves: khalf = wid>>1, nhalf = wid&1. Each wave: 64x64 tile over K=512 half
// -> 16 ks-steps of K=32, 16 MFMA + 8 coalesced L2 dwordx4 loads per step.
// NO LDS / NO barriers in main loop; depth-3 NAMED register sets (rule #20).
// Epilogue: khalf1 dumps acc to LDS once; khalf0 adds, applies bias, stores.
__global__ __launch_bounds__(256, 1)
void gemm_reg_kernel(const short* __restrict__ At, const short* __restrict__ Bt,
                     const float* __restrict__ biasf, float* __restrict__ out)
{
    __shared__ float red[2][16][64][4];   // [nhalf][frag m*4+n][lane][4] = 32 KB

    const int tid  = threadIdx.x;
    const int lane = tid & 63;
    const int wid  = tid >> 6;           // 0..3
    const int khalf = wid >> 1;
    const int nhalf = wid & 1;
    const int bid  = blockIdx.x;
    const int Mtile = bid & 63;          // XCD = bid%8 = Mtile%8 -> 2MB/XCD working set
    const int Ntile = bid >> 6;          // 0..3

    const char* pA[4];
    const char* pB[4];
#pragma unroll
    for (int m = 0; m < 4; ++m)
        pA[m] = (const char*)At + ((size_t)(Mtile * 4 + m) << 15)
              + (size_t)khalf * 16 * 1024 + lane * 16;
#pragma unroll
    for (int n = 0; n < 4; ++n)
        pB[n] = (const char*)Bt + ((size_t)(Ntile * 8 + nhalf * 4 + n) << 15)
              + (size_t)khalf * 16 * 1024 + lane * 16;

    f32x4 acc[4][4];
#pragma unroll
    for (int m = 0; m < 4; ++m)
#pragma unroll
        for (int n = 0; n < 4; ++n) acc[m][n] = (f32x4)0.0f;

    bf16x8 a0[4], b0[4], a1[4], b1[4], a2[4], b2[4];

#define LOADSET(sa, sb, KS) do {                                              \
    _Pragma("unroll") for (int m_ = 0; m_ < 4; ++m_)                          \
        sa[m_] = *(const bf16x8*)(pA[m_] + (size_t)(KS) * 1024);              \
    _Pragma("unroll") for (int n_ = 0; n_ < 4; ++n_)                          \
        sb[n_] = *(const bf16x8*)(pB[n_] + (size_t)(KS) * 1024);              \
} while (0)

#define COMPSET(sa, sb) do {                                                  \
    _Pragma("unroll") for (int m_ = 0; m_ < 4; ++m_)                          \
    _Pragma("unroll") for (int n_ = 0; n_ < 4; ++n_)                          \
        acc[m_][n_] = __builtin_amdgcn_mfma_f32_16x16x32_bf16(                \
            sa[m_], sb[n_], acc[m_][n_], 0, 0, 0);                            \
} while (0)

    LOADSET(a0, b0, 0);
    LOADSET(a1, b1, 1);
    LOADSET(a2, b2, 2);

#pragma unroll
    for (int i = 0; i < 15; i += 3) {     // i = 0,3,6,9,12 ; all indices literal
        COMPSET(a0, b0); if (i + 3 < 16) LOADSET(a0, b0, i + 3);
        COMPSET(a1, b1); if (i + 4 < 16) LOADSET(a1, b1, i + 4);
        COMPSET(a2, b2); if (i + 5 < 16) LOADSET(a2, b2, i + 5);
    }
    COMPSET(a0, b0);                      // ks = 15

#undef LOADSET
#undef COMPSET

    // ---- split-K reduce through LDS (once) ----
    if (khalf == 1) {
#pragma unroll
        for (int m = 0; m < 4; ++m)
#pragma unroll
            for (int n = 0; n < 4; ++n)
                *(f32x4*)&red[nhalf][m * 4 + n][lane][0] = acc[m][n];
    }
    __syncthreads();
    if (khalf == 0) {
#pragma unroll
        for (int m = 0; m < 4; ++m)
#pragma unroll
            for (int n = 0; n < 4; ++n)
                acc[m][n] += *(const f32x4*)&red[nhalf][m * 4 + n][lane][0];

        // D layout: col = lane&15, row = (lane>>4)*4 + r (verified m89/m91 + R4).
#pragma unroll
        for (int n = 0; n < 4; ++n) {
            const int j = Ntile * 128 + nhalf * 64 + n * 16 + (lane & 15);
            const float bias = biasf[j];
#pragma unroll
            for (int m = 0; m < 4; ++m) {
                const int i0 = Mtile * 64 + m * 16 + ((lane >> 4) << 2);
#pragma unroll
                for (int r = 0; r < 4; ++r)
                    out[(size_t)(i0 + r) * Ndim + j] = acc[m][n][r] + bias;
            }
        }
    }
}

// ==================== fallback (round-1 fused kernel, proven 17.55us) ====================
DEVFN int swz_fb(int row, int colByte) { return row * 128 + (colByte ^ ((row & 7) << 4)); }

__global__ __launch_bounds__(512, 2)
void fused_proj_kernel(const float* __restrict__ S, const float* __restrict__ L,
                       const float* __restrict__ Ws, const float* __restrict__ Wl,
                       const float* __restrict__ bs, const float* __restrict__ bl,
                       float* __restrict__ out)
{
    __shared__ char smA[2][128 * 64 * 2];
    __shared__ char smB[2][64 * 64 * 2];
    const int tid = threadIdx.x, bid = blockIdx.x;
    const int Mbase = (bid & 31) * 128, Nbase = (bid >> 5) * 64;
    const int srow = tid >> 4, scol = (tid & 15) * 4;
    const int lane = tid & 63, wid = tid >> 6, wr = wid >> 1, wc = wid & 1;

    f32x4 acc[2][2];
#pragma unroll
    for (int m = 0; m < 2; ++m)
#pragma unroll
        for (int n = 0; n < 2; ++n) acc[m][n] = (f32x4)0.0f;
    float4 av[4]; float4 bv[2];

    auto loadTiles = [&](int kt) {
        const float* sA = (kt < 8) ? S : L;
        const float* sB = (kt < 8) ? Ws : Wl;
        const int kOff = (kt & 7) * 64 + scol;
#pragma unroll
        for (int q = 0; q < 4; ++q)
            av[q] = *(const float4*)(sA + (size_t)(Mbase + q * 32 + srow) * Dk + kOff);
#pragma unroll
        for (int q = 0; q < 2; ++q)
            bv[q] = *(const float4*)(sB + (size_t)(Nbase + q * 32 + srow) * Dk + kOff);
    };
    auto writeTiles = [&](int p, float scB) {
#pragma unroll
        for (int q = 0; q < 4; ++q) {
            bf16x4 v = { f2bf(av[q].x), f2bf(av[q].y), f2bf(av[q].z), f2bf(av[q].w) };
            *(bf16x4*)(&smA[p][swz_fb(q * 32 + srow, scol * 2)]) = v;
        }
#pragma unroll
        for (int q = 0; q < 2; ++q) {
            bf16x4 v = { f2bf(bv[q].x * scB), f2bf(bv[q].y * scB),
                         f2bf(bv[q].z * scB), f2bf(bv[q].w * scB) };
            *(bf16x4*)(&smB[p][swz_fb(q * 32 + srow, scol * 2)]) = v;
        }
    };

    loadTiles(0); writeTiles(0, W_S); loadTiles(1);
    __syncthreads();
    for (int kt = 0; kt < 16; ++kt) {
        const int p = kt & 1;
#pragma unroll
        for (int kk = 0; kk < 2; ++kk) {
            bf16x8 a[2], b[2];
            const int cb = kk * 64 + (lane >> 4) * 16;
#pragma unroll
            for (int m = 0; m < 2; ++m)
                a[m] = *(const bf16x8*)(&smA[p][swz_fb(wr * 32 + m * 16 + (lane & 15), cb)]);
#pragma unroll
            for (int n = 0; n < 2; ++n)
                b[n] = *(const bf16x8*)(&smB[p][swz_fb(wc * 32 + n * 16 + (lane & 15), cb)]);
#pragma unroll
            for (int m = 0; m < 2; ++m)
#pragma unroll
                for (int n = 0; n < 2; ++n)
                    acc[m][n] = __builtin_amdgcn_mfma_f32_16x16x32_bf16(a[m], b[n], acc[m][n], 0, 0, 0);
        }
        if (kt + 1 < 16) {
            writeTiles(p ^ 1, (kt + 1 < 8) ? W_S : W_L);
            if (kt + 2 < 16) loadTiles(kt + 2);
            __syncthreads();
        }
    }
#pragma unroll
    for (int n = 0; n < 2; ++n) {
        const int j = Nbase + wc * 32 + n * 16 + (lane & 15);
        const float bias = W_S * bs[j] + W_L * bl[j];
#pragma unroll
        for (int m = 0; m < 2; ++m) {
            const int i0 = Mbase + wr * 32 + m * 16 + ((lane >> 4) << 2);
#pragma unroll
            for (int r = 0; r < 4; ++r)
                out[(size_t)(i0 + r) * Ndim + j] = acc[m][n][r] + bias;
        }
    }
}

extern "C" void kernel_launch(void* const* d_in, const int* in_sizes, int n_in,
                              void* d_out, int out_size, void* d_ws, size_t ws_size,
                              hipStream_t stream) {
    const float* S  = (const float*)d_in[0];
    const float* L  = (const float*)d_in[1];
    const float* Ws = (const float*)d_in[2];
    const float* bs = (const float*)d_in[3];
    const float* Wl = (const float*)d_in[4];
    const float* bl = (const float*)d_in[5];
    // d_in[6] = sigma: dead code in reference output.

    if (ws_size >= WS_NEEDED) {
        short* At    = (short*)d_ws;
        short* Bt    = (short*)((char*)d_ws + ABF_BYTES);
        float* biasf = (float*)((char*)d_ws + ABF_BYTES + BBF_BYTES);
        const int pre_blocks = (TOT_UNITS + 255) / 256;
        prepass_kernel<<<pre_blocks, 256, 0, stream>>>(S, L, Ws, Wl, bs, bl, At, Bt, biasf);
        gemm_reg_kernel<<<256, 256, 0, stream>>>(At, Bt, biasf, (float*)d_out);
    } else {
        fused_proj_kernel<<<256, 512, 0, stream>>>(S, L, Ws, Wl, bs, bl, (float*)d_out);
    }
}

// Round 6
// 31.628 us; speedup vs baseline: 1.3215x; 1.0048x over previous
//
#include <hip/hip_runtime.h>
#include <hip/hip_bf16.h>

typedef __attribute__((ext_vector_type(4))) float f32x4;
typedef __attribute__((ext_vector_type(8))) short bf16x8;
typedef __attribute__((ext_vector_type(4))) short bf16x4;

#define DEVFN static __device__ __forceinline__

constexpr int Mdim = 4096;
constexpr int Ndim = 512;
constexpr int Dk   = 512;
constexpr float W_S = 0.6224593312018546f;   // sigmoid(0.5)
constexpr float W_L = 1.0f - W_S;

DEVFN short f2bf(float x) {
    __hip_bfloat16 h = __float2bfloat16(x);   // RNE
    return *reinterpret_cast<short*>(&h);
}

// ============================ B-prepass (tiny: 3 MB traffic) ============================
// ws: Bbf[512][1024] bf16 row-major, scale folded (W_S for k<512, W_L for k>=512)
//     biasf[512] f32 = W_S*bs + W_L*bl
constexpr int BW_UNITS   = (Ndim * 2 * Dk) / 8;   // 65536
constexpr int BIAS_UNITS = Ndim / 8;              // 64
constexpr size_t BBF_BYTES = (size_t)Ndim * 2 * Dk * 2;   // 1 MB
constexpr size_t WS_NEEDED = BBF_BYTES + Ndim * 4;

__global__ __launch_bounds__(256)
void bprep_kernel(const float* __restrict__ Ws, const float* __restrict__ Wl,
                  const float* __restrict__ bs, const float* __restrict__ bl,
                  short* __restrict__ Bbf, float* __restrict__ biasf)
{
    const int t = blockIdx.x * blockDim.x + threadIdx.x;
    if (t < BW_UNITS) {
        const int row = t >> 7;            // 0..511 (W row = output col)
        const int col = (t & 127) * 8;     // 0..1016 virtual k
        const bool sm = (col < Dk);
        const float* src = sm ? (Ws + (size_t)row * Dk + col)
                              : (Wl + (size_t)row * Dk + (col - Dk));
        const float sc = sm ? W_S : W_L;
        float4 v0 = *(const float4*)src;
        float4 v1 = *(const float4*)(src + 4);
        bf16x8 o = { f2bf(v0.x*sc), f2bf(v0.y*sc), f2bf(v0.z*sc), f2bf(v0.w*sc),
                     f2bf(v1.x*sc), f2bf(v1.y*sc), f2bf(v1.z*sc), f2bf(v1.w*sc) };
        *(bf16x8*)(Bbf + (size_t)t * 8) = o;
    } else if (t < BW_UNITS + BIAS_UNITS) {
        const int j = (t - BW_UNITS) * 8;
        float4 s0 = *(const float4*)(bs + j), s1 = *(const float4*)(bs + j + 4);
        float4 l0 = *(const float4*)(bl + j), l1 = *(const float4*)(bl + j + 4);
        float4 o0 = { W_S*s0.x + W_L*l0.x, W_S*s0.y + W_L*l0.y,
                      W_S*s0.z + W_L*l0.z, W_S*s0.w + W_L*l0.w };
        float4 o1 = { W_S*s1.x + W_L*l1.x, W_S*s1.y + W_L*l1.y,
                      W_S*s1.z + W_L*l1.z, W_S*s1.w + W_L*l1.w };
        *(float4*)(biasf + j)     = o0;
        *(float4*)(biasf + j + 4) = o1;
    }
}

// ============================ split-K LDS GEMM (single pass over A) ============================
// C[4096][512] = [S|L] @ Bbf^T + biasf.  BM=64, BN=128, BK=128, 8 steps.
// grid 256 (1 blk/CU), 256 thr = 4 waves (khalf=wid>>1, nhalf=wid&1), wave tile 64x64.
// A converted f32->bf16 in-kernel (re-read only x4); B read as bf16 (prepped once).
// Per step per wave: issue loads(kt+1) -> compute(kt): 16 ds_read_b128 + 32 MFMA
//   -> convert+ds_write(kt+1) -> one barrier.  XOR swizzle (row&7)<<4 (2-way, free).
__global__ __launch_bounds__(256, 1)
void gemm_splitk_kernel(const float* __restrict__ S, const float* __restrict__ L,
                        const short* __restrict__ Bbf, const float* __restrict__ biasf,
                        float* __restrict__ out)
{
    __shared__ char  smA[2][16 * 1024];          // 64 rows x 256B
    __shared__ char  smB[2][32 * 1024];          // 128 rows x 256B
    __shared__ float red[2][16][64][4];          // 32 KB split-K reduce

    const int tid  = threadIdx.x;
    const int lane = tid & 63;
    const int wid  = tid >> 6;
    const int khalf = wid >> 1;
    const int nhalf = wid & 1;
    const int Mtile = blockIdx.x & 63;           // XCD = bid%8 = Mtile%8 (A-panel affinity)
    const int Ntile = blockIdx.x >> 6;
    const int Mbase = Mtile * 64;
    const int Nbase = Ntile * 128;

    // staging assignment
    const int arow = tid >> 2;                   // 0..63
    const int acol = (tid & 3) * 32;             // f32 col within 128-window
    const int brow = tid >> 1;                   // 0..127
    const int bcolB = (tid & 1) * 128;           // byte col within 256B row window

    float4 afv[8];                               // 32 A f32 prefetched
    bf16x8 bfv[8];                               // 128 B of B bf16 prefetched

    auto loadStep = [&](int kt) {
        const float* sA = (kt < 4) ? S : L;
        const float* pa = sA + (size_t)(Mbase + arow) * Dk + (kt & 3) * 128 + acol;
#pragma unroll
        for (int q = 0; q < 8; ++q)
            afv[q] = *(const float4*)(pa + q * 4);
        const short* pb = Bbf + (size_t)(Nbase + brow) * 1024 + kt * 128;
#pragma unroll
        for (int q = 0; q < 8; ++q)
            bfv[q] = *(const bf16x8*)((const char*)pb + bcolB + q * 16);
    };

    auto writeStep = [&](int p) {
        const int aswz = (arow & 7) << 4;
#pragma unroll
        for (int q = 0; q < 4; ++q) {
            bf16x8 v = { f2bf(afv[2*q].x),   f2bf(afv[2*q].y),
                         f2bf(afv[2*q].z),   f2bf(afv[2*q].w),
                         f2bf(afv[2*q+1].x), f2bf(afv[2*q+1].y),
                         f2bf(afv[2*q+1].z), f2bf(afv[2*q+1].w) };
            const int byte = (tid & 3) * 64 + q * 16;
            *(bf16x8*)(&smA[p][arow * 256 + (byte ^ aswz)]) = v;
        }
        const int bswz = (brow & 7) << 4;
#pragma unroll
        for (int q = 0; q < 8; ++q) {
            const int byte = bcolB + q * 16;
            *(bf16x8*)(&smB[p][brow * 256 + (byte ^ bswz)]) = bfv[q];
        }
    };

    f32x4 acc[4][4];
#pragma unroll
    for (int m = 0; m < 4; ++m)
#pragma unroll
        for (int n = 0; n < 4; ++n) acc[m][n] = (f32x4)0.0f;

    auto compute = [&](int p) {
#pragma unroll
        for (int kk = 0; kk < 2; ++kk) {
            const int cb = khalf * 128 + kk * 64 + (lane >> 4) * 16;
            bf16x8 a[4], b[4];
#pragma unroll
            for (int m = 0; m < 4; ++m) {
                const int r = m * 16 + (lane & 15);
                a[m] = *(const bf16x8*)(&smA[p][r * 256 + (cb ^ ((r & 7) << 4))]);
            }
#pragma unroll
            for (int n = 0; n < 4; ++n) {
                const int r = nhalf * 64 + n * 16 + (lane & 15);
                b[n] = *(const bf16x8*)(&smB[p][r * 256 + (cb ^ ((r & 7) << 4))]);
            }
#pragma unroll
            for (int m = 0; m < 4; ++m)
#pragma unroll
                for (int n = 0; n < 4; ++n)
                    acc[m][n] = __builtin_amdgcn_mfma_f32_16x16x32_bf16(a[m], b[n], acc[m][n], 0, 0, 0);
        }
    };

    // prologue
    loadStep(0);
    writeStep(0);
    __syncthreads();

#pragma unroll
    for (int kt = 0; kt < 8; ++kt) {
        const int p = kt & 1;
        if (kt < 7) loadStep(kt + 1);    // in flight across compute (T14)
        compute(p);
        if (kt < 7) writeStep(p ^ 1);    // waits loads via dependency only
        __syncthreads();                 // publish buf p^1; retire reads of p
    }

    // split-K reduce (structure proven in R5, absmax 0.0078)
    if (khalf == 1) {
#pragma unroll
        for (int m = 0; m < 4; ++m)
#pragma unroll
            for (int n = 0; n < 4; ++n)
                *(f32x4*)&red[nhalf][m * 4 + n][lane][0] = acc[m][n];
    }
    __syncthreads();
    if (khalf == 0) {
#pragma unroll
        for (int m = 0; m < 4; ++m)
#pragma unroll
            for (int n = 0; n < 4; ++n)
                acc[m][n] += *(const f32x4*)&red[nhalf][m * 4 + n][lane][0];

        // D layout: col = lane&15, row = (lane>>4)*4 + r (verified m89/m91 + R4/R5)
#pragma unroll
        for (int n = 0; n < 4; ++n) {
            const int j = Nbase + nhalf * 64 + n * 16 + (lane & 15);
            const float bias = biasf[j];
#pragma unroll
            for (int m = 0; m < 4; ++m) {
                const int i0 = Mbase + m * 16 + ((lane >> 4) << 2);
#pragma unroll
                for (int r = 0; r < 4; ++r)
                    out[(size_t)(i0 + r) * Ndim + j] = acc[m][n][r] + bias;
            }
        }
    }
}

// ==================== fallback (round-1 fused kernel, proven 17.55us) ====================
DEVFN int swz_fb(int row, int colByte) { return row * 128 + (colByte ^ ((row & 7) << 4)); }

__global__ __launch_bounds__(512, 2)
void fused_proj_kernel(const float* __restrict__ S, const float* __restrict__ L,
                       const float* __restrict__ Ws, const float* __restrict__ Wl,
                       const float* __restrict__ bs, const float* __restrict__ bl,
                       float* __restrict__ out)
{
    __shared__ char smA[2][128 * 64 * 2];
    __shared__ char smB[2][64 * 64 * 2];
    const int tid = threadIdx.x, bid = blockIdx.x;
    const int Mbase = (bid & 31) * 128, Nbase = (bid >> 5) * 64;
    const int srow = tid >> 4, scol = (tid & 15) * 4;
    const int lane = tid & 63, wid = tid >> 6, wr = wid >> 1, wc = wid & 1;

    f32x4 acc[2][2];
#pragma unroll
    for (int m = 0; m < 2; ++m)
#pragma unroll
        for (int n = 0; n < 2; ++n) acc[m][n] = (f32x4)0.0f;
    float4 av[4]; float4 bv[2];

    auto loadTiles = [&](int kt) {
        const float* sA = (kt < 8) ? S : L;
        const float* sB = (kt < 8) ? Ws : Wl;
        const int kOff = (kt & 7) * 64 + scol;
#pragma unroll
        for (int q = 0; q < 4; ++q)
            av[q] = *(const float4*)(sA + (size_t)(Mbase + q * 32 + srow) * Dk + kOff);
#pragma unroll
        for (int q = 0; q < 2; ++q)
            bv[q] = *(const float4*)(sB + (size_t)(Nbase + q * 32 + srow) * Dk + kOff);
    };
    auto writeTiles = [&](int p, float scB) {
#pragma unroll
        for (int q = 0; q < 4; ++q) {
            bf16x4 v = { f2bf(av[q].x), f2bf(av[q].y), f2bf(av[q].z), f2bf(av[q].w) };
            *(bf16x4*)(&smA[p][swz_fb(q * 32 + srow, scol * 2)]) = v;
        }
#pragma unroll
        for (int q = 0; q < 2; ++q) {
            bf16x4 v = { f2bf(bv[q].x * scB), f2bf(bv[q].y * scB),
                         f2bf(bv[q].z * scB), f2bf(bv[q].w * scB) };
            *(bf16x4*)(&smB[p][swz_fb(q * 32 + srow, scol * 2)]) = v;
        }
    };

    loadTiles(0); writeTiles(0, W_S); loadTiles(1);
    __syncthreads();
    for (int kt = 0; kt < 16; ++kt) {
        const int p = kt & 1;
#pragma unroll
        for (int kk = 0; kk < 2; ++kk) {
            bf16x8 a[2], b[2];
            const int cb = kk * 64 + (lane >> 4) * 16;
#pragma unroll
            for (int m = 0; m < 2; ++m)
                a[m] = *(const bf16x8*)(&smA[p][swz_fb(wr * 32 + m * 16 + (lane & 15), cb)]);
#pragma unroll
            for (int n = 0; n < 2; ++n)
                b[n] = *(const bf16x8*)(&smB[p][swz_fb(wc * 32 + n * 16 + (lane & 15), cb)]);
#pragma unroll
            for (int m = 0; m < 2; ++m)
#pragma unroll
                for (int n = 0; n < 2; ++n)
                    acc[m][n] = __builtin_amdgcn_mfma_f32_16x16x32_bf16(a[m], b[n], acc[m][n], 0, 0, 0);
        }
        if (kt + 1 < 16) {
            writeTiles(p ^ 1, (kt + 1 < 8) ? W_S : W_L);
            if (kt + 2 < 16) loadTiles(kt + 2);
            __syncthreads();
        }
    }
#pragma unroll
    for (int n = 0; n < 2; ++n) {
        const int j = Nbase + wc * 32 + n * 16 + (lane & 15);
        const float bias = W_S * bs[j] + W_L * bl[j];
#pragma unroll
        for (int m = 0; m < 2; ++m) {
            const int i0 = Mbase + wr * 32 + m * 16 + ((lane >> 4) << 2);
#pragma unroll
            for (int r = 0; r < 4; ++r)
                out[(size_t)(i0 + r) * Ndim + j] = acc[m][n][r] + bias;
        }
    }
}

extern "C" void kernel_launch(void* const* d_in, const int* in_sizes, int n_in,
                              void* d_out, int out_size, void* d_ws, size_t ws_size,
                              hipStream_t stream) {
    const float* S  = (const float*)d_in[0];
    const float* L  = (const float*)d_in[1];
    const float* Ws = (const float*)d_in[2];
    const float* bs = (const float*)d_in[3];
    const float* Wl = (const float*)d_in[4];
    const float* bl = (const float*)d_in[5];
    // d_in[6] = sigma: dead code in reference output.

    if (ws_size >= WS_NEEDED) {
        short* Bbf   = (short*)d_ws;
        float* biasf = (float*)((char*)d_ws + BBF_BYTES);
        const int bp_blocks = (BW_UNITS + BIAS_UNITS + 255) / 256;
        bprep_kernel<<<bp_blocks, 256, 0, stream>>>(Ws, Wl, bs, bl, Bbf, biasf);
        gemm_splitk_kernel<<<256, 256, 0, stream>>>(S, L, Bbf, biasf, (float*)d_out);
    } else {
        fused_proj_kernel<<<256, 512, 0, stream>>>(S, L, Ws, Wl, bs, bl, (float*)d_out);
    }
}

// Round 7
// 25.559 us; speedup vs baseline: 1.6353x; 1.2375x over previous
//
#include <hip/hip_runtime.h>
#include <hip/hip_bf16.h>

typedef __attribute__((ext_vector_type(4))) float f32x4;
typedef __attribute__((ext_vector_type(8))) short bf16x8;
typedef __attribute__((ext_vector_type(4))) short bf16x4;

#define DEVFN static __device__ __forceinline__

constexpr int Mdim = 4096;
constexpr int Ndim = 512;
constexpr int Dk   = 512;
constexpr float W_S = 0.6224593312018546f;   // sigmoid(0.5)
constexpr float W_L = 1.0f - W_S;

DEVFN short f2bf(float x) {
    __hip_bfloat16 h = __float2bfloat16(x);   // RNE
    return *reinterpret_cast<short*>(&h);
}

// ============================ prepass: fragment-tiled B + bias ============================
// Bt layout (R4-proven): [g=col/16][ks=k/32][lane]*16B with lane = ((k/8)&3)*16 + (col&15)
// scale folded: W_S for k<512 (Ws), W_L for k>=512 (Wl).  biasf = W_S*bs + W_L*bl.
constexpr int B_UNITS    = (Ndim * 2 * Dk) / 8;   // 65536
constexpr int BIAS_UNITS = Ndim / 8;              // 64
constexpr size_t BT_BYTES  = (size_t)Ndim * 2 * Dk * 2;   // 1 MB
constexpr size_t WS_NEEDED = BT_BYTES + Ndim * 4;

__global__ __launch_bounds__(256)
void bprep_kernel(const float* __restrict__ Ws, const float* __restrict__ Wl,
                  const float* __restrict__ bs, const float* __restrict__ bl,
                  short* __restrict__ Bt, float* __restrict__ biasf)
{
    const int t = blockIdx.x * blockDim.x + threadIdx.x;
    if (t < B_UNITS) {
        const int l  = t & 63;
        const int ks = (t >> 6) & 31;
        const int g  = t >> 11;                 // 0..31
        const int row = g * 16 + (l & 15);      // W row = output col
        const int k0  = ks * 32 + (l >> 4) * 8;
        const bool sm = (k0 < Dk);
        const float* src = sm ? (Ws + (size_t)row * Dk + k0)
                              : (Wl + (size_t)row * Dk + (k0 - Dk));
        const float sc = sm ? W_S : W_L;
        float4 v0 = *(const float4*)src;
        float4 v1 = *(const float4*)(src + 4);
        bf16x8 o = { f2bf(v0.x*sc), f2bf(v0.y*sc), f2bf(v0.z*sc), f2bf(v0.w*sc),
                     f2bf(v1.x*sc), f2bf(v1.y*sc), f2bf(v1.z*sc), f2bf(v1.w*sc) };
        *(bf16x8*)(Bt + (size_t)t * 8) = o;
    } else if (t < B_UNITS + BIAS_UNITS) {
        const int j = (t - B_UNITS) * 8;
        float4 s0 = *(const float4*)(bs + j), s1 = *(const float4*)(bs + j + 4);
        float4 l0 = *(const float4*)(bl + j), l1 = *(const float4*)(bl + j + 4);
        float4 o0 = { W_S*s0.x + W_L*l0.x, W_S*s0.y + W_L*l0.y,
                      W_S*s0.z + W_L*l0.z, W_S*s0.w + W_L*l0.w };
        float4 o1 = { W_S*s1.x + W_L*l1.x, W_S*s1.y + W_L*l1.y,
                      W_S*s1.z + W_L*l1.z, W_S*s1.w + W_L*l1.w };
        *(float4*)(biasf + j)     = o0;
        *(float4*)(biasf + j + 4) = o1;
    }
}

// ============================ main GEMM ============================
// C[4096][512] = [S|L](f32, converted in-kernel) @ Bt^T(bf16) + biasf.
// grid 256 (1 blk/CU), 512 thr = 8 waves: kq = wid&3 (K-quarter), nh = wid>>2.
// Wave tile 64x64 over its 256-k quarter. Phase1: stage A 64x1024 bf16 into
// 128KB LDS (one barrier). Phase2: barrier-free MFMA stream; B direct from L2.
// Phase3: split-K-4 reduce through reused smA space; bias; store.
__global__ __launch_bounds__(512, 1)
void gemm_bdirect_kernel(const float* __restrict__ S, const float* __restrict__ L,
                         const short* __restrict__ Bt, const float* __restrict__ biasf,
                         float* __restrict__ out)
{
    __shared__ char smA[64 * 2048];       // 128 KB: [row][2048B = 1024 k bf16], swizzled

    const int tid  = threadIdx.x;
    const int lane = tid & 63;
    const int wid  = tid >> 6;            // 0..7
    const int kq   = wid & 3;             // K-quarter
    const int nh   = wid >> 2;            // N-half
    const int Mtile = blockIdx.x & 63;    // XCD = bid%8 = Mtile%8 (A-panel affinity)
    const int Ntile = blockIdx.x >> 6;    // 0..3
    const int Mbase = Mtile * 64;

    // ---- Phase 1: stage A (S ++ L, 64 rows x 1024 k) as bf16 into LDS ----
    {
        const int row = tid & 63;
        const int cg  = tid >> 6;          // 0..7, 128-col window
        const float* src = (cg < 4) ? (S + (size_t)(Mbase + row) * Dk + cg * 128)
                                    : (L + (size_t)(Mbase + row) * Dk + (cg - 4) * 128);
        const int swz = (row & 7) << 4;
        const int base = row * 2048 + cg * 256;
#pragma unroll
        for (int q = 0; q < 16; ++q) {     // 16 x (8 f32 -> 8 bf16, 16B store)
            float4 v0 = *(const float4*)(src + q * 8);
            float4 v1 = *(const float4*)(src + q * 8 + 4);
            bf16x8 o = { f2bf(v0.x), f2bf(v0.y), f2bf(v0.z), f2bf(v0.w),
                         f2bf(v1.x), f2bf(v1.y), f2bf(v1.z), f2bf(v1.w) };
            *(bf16x8*)(&smA[base + ((q * 16) ^ swz)]) = o;
        }
    }
    __syncthreads();                       // barrier #1 (of 3)

    // ---- Phase 2: barrier-free MFMA stream over this wave's K-quarter ----
    const char* pB[4];
#pragma unroll
    for (int n = 0; n < 4; ++n)
        pB[n] = (const char*)Bt + ((size_t)(Ntile * 8 + nh * 4 + n) << 15) + lane * 16;

    f32x4 acc[4][4];
#pragma unroll
    for (int m = 0; m < 4; ++m)
#pragma unroll
        for (int n = 0; n < 4; ++n) acc[m][n] = (f32x4)0.0f;

    bf16x8 a[4], b0[4], b1[4];

#define LOADB(dst, s) do {                                                    \
    const int ks_ = kq * 8 + (s);                                             \
    _Pragma("unroll") for (int n_ = 0; n_ < 4; ++n_)                          \
        dst[n_] = *(const bf16x8*)(pB[n_] + (size_t)ks_ * 1024);              \
} while (0)

#define LOADA(s) do {                                                         \
    const int cb_ = (kq * 8 + (s)) * 64 + (lane >> 4) * 16;                   \
    _Pragma("unroll") for (int m_ = 0; m_ < 4; ++m_) {                        \
        const int r_ = m_ * 16 + (lane & 15);                                 \
        a[m_] = *(const bf16x8*)(&smA[r_ * 2048 + (cb_ ^ ((r_ & 7) << 4))]);  \
    }                                                                         \
} while (0)

#define COMP(bb) do {                                                         \
    _Pragma("unroll") for (int m_ = 0; m_ < 4; ++m_)                          \
    _Pragma("unroll") for (int n_ = 0; n_ < 4; ++n_)                          \
        acc[m_][n_] = __builtin_amdgcn_mfma_f32_16x16x32_bf16(                \
            a[m_], bb[n_], acc[m_][n_], 0, 0, 0);                             \
} while (0)

    LOADB(b0, 0);
    LOADB(b1, 1); LOADA(0); COMP(b0);      // s=0
    LOADB(b0, 2); LOADA(1); COMP(b1);      // s=1
    LOADB(b1, 3); LOADA(2); COMP(b0);      // s=2
    LOADB(b0, 4); LOADA(3); COMP(b1);      // s=3
    LOADB(b1, 5); LOADA(4); COMP(b0);      // s=4
    LOADB(b0, 6); LOADA(5); COMP(b1);      // s=5
    LOADB(b1, 7); LOADA(6); COMP(b0);      // s=6
                  LOADA(7); COMP(b1);      // s=7

#undef LOADB
#undef LOADA
#undef COMP

    // ---- Phase 3: split-K-4 reduce through reused smA; bias; store ----
    __syncthreads();                       // barrier #2: all smA reads done
    float* red = (float*)smA;              // 6 waves x 16KB = 96KB < 128KB
    if (kq != 0) {
        const int w6 = (kq - 1) * 2 + nh;  // 0..5
#pragma unroll
        for (int m = 0; m < 4; ++m)
#pragma unroll
            for (int n = 0; n < 4; ++n)
                *(f32x4*)&red[(size_t)w6 * 4096 + (m * 4 + n) * 256 + lane * 4] = acc[m][n];
    }
    __syncthreads();                       // barrier #3: dumps visible
    if (kq == 0) {
#pragma unroll
        for (int p = 0; p < 3; ++p)
#pragma unroll
            for (int m = 0; m < 4; ++m)
#pragma unroll
                for (int n = 0; n < 4; ++n)
                    acc[m][n] += *(const f32x4*)&red[(size_t)(p * 2 + nh) * 4096 + (m * 4 + n) * 256 + lane * 4];

        // D layout: col = lane&15, row = (lane>>4)*4 + r (verified m89/m91 + R4/R5/R6)
#pragma unroll
        for (int n = 0; n < 4; ++n) {
            const int j = Ntile * 128 + nh * 64 + n * 16 + (lane & 15);
            const float bias = biasf[j];
#pragma unroll
            for (int m = 0; m < 4; ++m) {
                const int i0 = Mbase + m * 16 + ((lane >> 4) << 2);
#pragma unroll
                for (int r = 0; r < 4; ++r)
                    out[(size_t)(i0 + r) * Ndim + j] = acc[m][n][r] + bias;
            }
        }
    }
}

// ==================== fallback (round-1 fused kernel, proven 17.55us) ====================
DEVFN int swz_fb(int row, int colByte) { return row * 128 + (colByte ^ ((row & 7) << 4)); }

__global__ __launch_bounds__(512, 2)
void fused_proj_kernel(const float* __restrict__ S, const float* __restrict__ L,
                       const float* __restrict__ Ws, const float* __restrict__ Wl,
                       const float* __restrict__ bs, const float* __restrict__ bl,
                       float* __restrict__ out)
{
    __shared__ char smA[2][128 * 64 * 2];
    __shared__ char smB[2][64 * 64 * 2];
    const int tid = threadIdx.x, bid = blockIdx.x;
    const int Mbase = (bid & 31) * 128, Nbase = (bid >> 5) * 64;
    const int srow = tid >> 4, scol = (tid & 15) * 4;
    const int lane = tid & 63, wid = tid >> 6, wr = wid >> 1, wc = wid & 1;

    f32x4 acc[2][2];
#pragma unroll
    for (int m = 0; m < 2; ++m)
#pragma unroll
        for (int n = 0; n < 2; ++n) acc[m][n] = (f32x4)0.0f;
    float4 av[4]; float4 bv[2];

    auto loadTiles = [&](int kt) {
        const float* sA = (kt < 8) ? S : L;
        const float* sB = (kt < 8) ? Ws : Wl;
        const int kOff = (kt & 7) * 64 + scol;
#pragma unroll
        for (int q = 0; q < 4; ++q)
            av[q] = *(const float4*)(sA + (size_t)(Mbase + q * 32 + srow) * Dk + kOff);
#pragma unroll
        for (int q = 0; q < 2; ++q)
            bv[q] = *(const float4*)(sB + (size_t)(Nbase + q * 32 + srow) * Dk + kOff);
    };
    auto writeTiles = [&](int p, float scB) {
#pragma unroll
        for (int q = 0; q < 4; ++q) {
            bf16x4 v = { f2bf(av[q].x), f2bf(av[q].y), f2bf(av[q].z), f2bf(av[q].w) };
            *(bf16x4*)(&smA[p][swz_fb(q * 32 + srow, scol * 2)]) = v;
        }
#pragma unroll
        for (int q = 0; q < 2; ++q) {
            bf16x4 v = { f2bf(bv[q].x * scB), f2bf(bv[q].y * scB),
                         f2bf(bv[q].z * scB), f2bf(bv[q].w * scB) };
            *(bf16x4*)(&smB[p][swz_fb(q * 32 + srow, scol * 2)]) = v;
        }
    };

    loadTiles(0); writeTiles(0, W_S); loadTiles(1);
    __syncthreads();
    for (int kt = 0; kt < 16; ++kt) {
        const int p = kt & 1;
#pragma unroll
        for (int kk = 0; kk < 2; ++kk) {
            bf16x8 a[2], b[2];
            const int cb = kk * 64 + (lane >> 4) * 16;
#pragma unroll
            for (int m = 0; m < 2; ++m)
                a[m] = *(const bf16x8*)(&smA[p][swz_fb(wr * 32 + m * 16 + (lane & 15), cb)]);
#pragma unroll
            for (int n = 0; n < 2; ++n)
                b[n] = *(const bf16x8*)(&smB[p][swz_fb(wc * 32 + n * 16 + (lane & 15), cb)]);
#pragma unroll
            for (int m = 0; m < 2; ++m)
#pragma unroll
                for (int n = 0; n < 2; ++n)
                    acc[m][n] = __builtin_amdgcn_mfma_f32_16x16x32_bf16(a[m], b[n], acc[m][n], 0, 0, 0);
        }
        if (kt + 1 < 16) {
            writeTiles(p ^ 1, (kt + 1 < 8) ? W_S : W_L);
            if (kt + 2 < 16) loadTiles(kt + 2);
            __syncthreads();
        }
    }
#pragma unroll
    for (int n = 0; n < 2; ++n) {
        const int j = Nbase + wc * 32 + n * 16 + (lane & 15);
        const float bias = W_S * bs[j] + W_L * bl[j];
#pragma unroll
        for (int m = 0; m < 2; ++m) {
            const int i0 = Mbase + wr * 32 + m * 16 + ((lane >> 4) << 2);
#pragma unroll
            for (int r = 0; r < 4; ++r)
                out[(size_t)(i0 + r) * Ndim + j] = acc[m][n][r] + bias;
        }
    }
}

extern "C" void kernel_launch(void* const* d_in, const int* in_sizes, int n_in,
                              void* d_out, int out_size, void* d_ws, size_t ws_size,
                              hipStream_t stream) {
    const float* S  = (const float*)d_in[0];
    const float* L  = (const float*)d_in[1];
    const float* Ws = (const float*)d_in[2];
    const float* bs = (const float*)d_in[3];
    const float* Wl = (const float*)d_in[4];
    const float* bl = (const float*)d_in[5];
    // d_in[6] = sigma: dead code in reference output.

    if (ws_size >= WS_NEEDED) {
        short* Bt    = (short*)d_ws;
        float* biasf = (float*)((char*)d_ws + BT_BYTES);
        const int bp_blocks = (B_UNITS + BIAS_UNITS + 255) / 256;
        bprep_kernel<<<bp_blocks, 256, 0, stream>>>(Ws, Wl, bs, bl, Bt, biasf);
        gemm_bdirect_kernel<<<256, 512, 0, stream>>>(S, L, Bt, biasf, (float*)d_out);
    } else {
        fused_proj_kernel<<<256, 512, 0, stream>>>(S, L, Ws, Wl, bs, bl, (float*)d_out);
    }
}

// Round 8
// 18.056 us; speedup vs baseline: 2.3148x; 1.4155x over previous
//
#include <hip/hip_runtime.h>
#include <hip/hip_bf16.h>

typedef __attribute__((ext_vector_type(4))) float f32x4;
typedef __attribute__((ext_vector_type(8))) short bf16x8;
typedef __attribute__((ext_vector_type(4))) short bf16x4;

#define DEVFN static __device__ __forceinline__

constexpr int Mdim = 4096;
constexpr int Ndim = 512;
constexpr int Dk   = 512;
constexpr float W_S = 0.6224593312018546f;   // sigmoid(0.5)
constexpr float W_L = 1.0f - W_S;

DEVFN short f2bf(float x) {
    __hip_bfloat16 h = __float2bfloat16(x);   // RNE
    return *reinterpret_cast<short*>(&h);
}

// XOR swizzle within 128B rows: 2-way bank aliasing on ds_read_b128 (free, m136).
DEVFN int swz(int row, int colByte) {
    return row * 128 + (colByte ^ ((row & 7) << 4));
}

// Single fused kernel (R1 structure, proven 17.55us / absmax 0.0078) +
// T14 async-stage split: tile kt+2's global loads issue at top of iter kt
// into the PING-PONG register set (statically named, rule #20), so their
// latency hides under compute(kt) + writeTiles(kt+1). In R1 the same
// registers held tile kt+1 (WAR hazard) forcing load-after-write.
__global__ __launch_bounds__(512, 2)
void fused_proj_kernel(const float* __restrict__ S, const float* __restrict__ L,
                       const float* __restrict__ Ws, const float* __restrict__ Wl,
                       const float* __restrict__ bs, const float* __restrict__ bl,
                       float* __restrict__ out)
{
    __shared__ char smA[2][128 * 64 * 2];   // 16 KB per buf
    __shared__ char smB[2][64 * 64 * 2];    // 8 KB per buf

    const int tid  = threadIdx.x;
    const int bid  = blockIdx.x;
    // Mtile = bid&31: XCD = bid%8 = Mtile%8 -> all 8 Ntile peers of an A-panel
    // share one XCD's L2 (A re-read x8 stays L2-local).
    const int Mbase = (bid & 31) * 128;
    const int Nbase = (bid >> 5) * 64;

    const int srow = tid >> 4;           // 0..31 staging row in a 32-row slab
    const int scol = (tid & 15) * 4;     // f32 col
    const int lane = tid & 63;
    const int wid  = tid >> 6;           // 0..7
    const int wr   = wid >> 1;           // 0..3
    const int wc   = wid & 1;            // 0..1

    f32x4 acc[2][2];
#pragma unroll
    for (int m = 0; m < 2; ++m)
#pragma unroll
        for (int n = 0; n < 2; ++n) acc[m][n] = (f32x4)0.0f;

    // Ping-pong register staging sets (named, never dynamically indexed).
    float4 avA[4], bvA[2];
    float4 avB[4], bvB[2];

    auto loadT = [&](float4 (&av)[4], float4 (&bv)[2], int kt) {
        const float* sA = (kt < 8) ? S : L;
        const float* sB = (kt < 8) ? Ws : Wl;
        const int kOff = (kt & 7) * 64 + scol;
#pragma unroll
        for (int q = 0; q < 4; ++q)
            av[q] = *(const float4*)(sA + (size_t)(Mbase + q * 32 + srow) * Dk + kOff);
#pragma unroll
        for (int q = 0; q < 2; ++q)
            bv[q] = *(const float4*)(sB + (size_t)(Nbase + q * 32 + srow) * Dk + kOff);
    };

    auto writeT = [&](float4 (&av)[4], float4 (&bv)[2], int p, float scB) {
#pragma unroll
        for (int q = 0; q < 4; ++q) {
            bf16x4 v = { f2bf(av[q].x), f2bf(av[q].y), f2bf(av[q].z), f2bf(av[q].w) };
            *(bf16x4*)(&smA[p][swz(q * 32 + srow, scol * 2)]) = v;
        }
#pragma unroll
        for (int q = 0; q < 2; ++q) {
            bf16x4 v = { f2bf(bv[q].x * scB), f2bf(bv[q].y * scB),
                         f2bf(bv[q].z * scB), f2bf(bv[q].w * scB) };
            *(bf16x4*)(&smB[p][swz(q * 32 + srow, scol * 2)]) = v;
        }
    };

    auto compute = [&](int p) {
#pragma unroll
        for (int kk = 0; kk < 2; ++kk) {
            bf16x8 a[2], b[2];
            const int cb = kk * 64 + (lane >> 4) * 16;
#pragma unroll
            for (int m = 0; m < 2; ++m)
                a[m] = *(const bf16x8*)(&smA[p][swz(wr * 32 + m * 16 + (lane & 15), cb)]);
#pragma unroll
            for (int n = 0; n < 2; ++n)
                b[n] = *(const bf16x8*)(&smB[p][swz(wc * 32 + n * 16 + (lane & 15), cb)]);
#pragma unroll
            for (int m = 0; m < 2; ++m)
#pragma unroll
                for (int n = 0; n < 2; ++n)
                    acc[m][n] = __builtin_amdgcn_mfma_f32_16x16x32_bf16(a[m], b[n], acc[m][n], 0, 0, 0);
        }
    };

    // Prologue: t0 staged to LDS0; t1 in setA; t2 in setB (in flight into iter 0).
    loadT(avA, bvA, 0);
    writeT(avA, bvA, 0, W_S);
    loadT(avA, bvA, 1);
    loadT(avB, bvB, 2);
    __syncthreads();

    // Schedule per iter kt (p = kt&1):
    //   issue load t(kt+2) into the set consumed LAST iter (kt>=1);
    //   compute(p);  write t(kt+1) from the OTHER set;  barrier.
    //   kt even -> write setA, load setB; kt odd -> write setB, load setA.
    for (int kt = 0; kt < 16; ++kt) {
        const int p = kt & 1;
        if (kt >= 1 && kt + 2 < 16) {
            if (kt & 1) loadT(avA, bvA, kt + 2);
            else        loadT(avB, bvB, kt + 2);
        }
        compute(p);
        if (kt + 1 < 16) {
            const float sc = (kt + 1 < 8) ? W_S : W_L;
            if (kt & 1) writeT(avB, bvB, p ^ 1, sc);
            else        writeT(avA, bvA, p ^ 1, sc);
        }
        __syncthreads();
    }

    // Epilogue: D layout col = lane&15, row = (lane>>4)*4 + r (verified m89/m91 + R1..R7).
#pragma unroll
    for (int n = 0; n < 2; ++n) {
        const int j = Nbase + wc * 32 + n * 16 + (lane & 15);
        const float bias = W_S * bs[j] + W_L * bl[j];
#pragma unroll
        for (int m = 0; m < 2; ++m) {
            const int i0 = Mbase + wr * 32 + m * 16 + ((lane >> 4) << 2);
#pragma unroll
            for (int r = 0; r < 4; ++r)
                out[(size_t)(i0 + r) * Ndim + j] = acc[m][n][r] + bias;
        }
    }
}

extern "C" void kernel_launch(void* const* d_in, const int* in_sizes, int n_in,
                              void* d_out, int out_size, void* d_ws, size_t ws_size,
                              hipStream_t stream) {
    const float* S  = (const float*)d_in[0];   // small_graph_features [4096,512]
    const float* L  = (const float*)d_in[1];   // large_graph_features [4096,512]
    const float* Ws = (const float*)d_in[2];   // W_small [512,512]
    const float* bs = (const float*)d_in[3];   // b_small [512]
    const float* Wl = (const float*)d_in[4];   // W_large [512,512]
    const float* bl = (const float*)d_in[5];   // b_large [512]
    // d_in[6] = sigma: dead code in the reference's output.

    const int grid = (Mdim / 128) * (Ndim / 64);   // 32*8 = 256 (1 block/CU)
    fused_proj_kernel<<<grid, 512, 0, stream>>>(S, L, Ws, Wl, bs, bl, (float*)d_out);
}

// Round 9
// 17.472 us; speedup vs baseline: 2.3921x; 1.0334x over previous
//
#include <hip/hip_runtime.h>
#include <hip/hip_bf16.h>

typedef __attribute__((ext_vector_type(4))) float f32x4;
typedef __attribute__((ext_vector_type(8))) short bf16x8;
typedef __attribute__((ext_vector_type(4))) short bf16x4;

#define DEVFN static __device__ __forceinline__

constexpr int Mdim = 4096;
constexpr int Ndim = 512;    // output cols
constexpr int Dk   = 512;    // K of each source matrix
constexpr int BM = 128, BN = 64, BK = 64;
constexpr int NKT = (2 * Dk) / BK;  // 16 K-tiles over the virtual K=1024 concat
constexpr float W_S = 0.6224593312018546f;   // sigmoid(0.5), compile-time const
constexpr float W_L = 1.0f - W_S;

DEVFN short f2bf(float x) {
    __hip_bfloat16 h = __float2bfloat16(x);   // RNE
    return *reinterpret_cast<short*>(&h);
}

// XOR swizzle: rows are 128B (64 bf16). Spreads the 16-lane same-column read
// across 8 16B slots -> 2-way bank aliasing (free). Bijective per row.
DEVFN int swz(int row, int colByte) {
    return row * 128 + (colByte ^ ((row & 7) << 4));
}

__global__ __launch_bounds__(512, 2)
void fused_proj_kernel(const float* __restrict__ S, const float* __restrict__ L,
                       const float* __restrict__ Ws, const float* __restrict__ Wl,
                       const float* __restrict__ bs, const float* __restrict__ bl,
                       float* __restrict__ out)
{
    __shared__ char smA[2][BM * BK * 2];   // 16 KB each
    __shared__ char smB[2][BN * BK * 2];   // 8 KB each

    const int tid  = threadIdx.x;
    const int bid  = blockIdx.x;
    // Mtile = bid&31: with round-robin XCD = bid%8, each XCD owns Mtiles
    // {x, x+8, x+16, x+24} across all Ntiles -> A rows reused within one XCD L2.
    const int Mtile = bid & 31;
    const int Ntile = bid >> 5;
    const int Mbase = Mtile * BM;
    const int Nbase = Ntile * BN;

    const int srow = tid >> 4;          // 0..31 staging row within a 32-row slab
    const int scol = (tid & 15) * 4;    // f32 col (0..60 step 4)
    const int lane = tid & 63;
    const int wid  = tid >> 6;          // 0..7
    const int wr   = wid >> 1;          // 0..3 -> 32-row slab
    const int wc   = wid & 1;           // 0..1 -> 32-col slab

    f32x4 acc[2][2];
#pragma unroll
    for (int m = 0; m < 2; ++m)
#pragma unroll
        for (int n = 0; n < 2; ++n)
            acc[m][n] = (f32x4)0.0f;

    float4 av[4];
    float4 bv[2];

    auto loadTiles = [&](int kt) {
        const float* sA = (kt < 8) ? S : L;
        const float* sB = (kt < 8) ? Ws : Wl;
        const int kOff = (kt & 7) * BK + scol;
#pragma unroll
        for (int q = 0; q < 4; ++q)
            av[q] = *(const float4*)(sA + (size_t)(Mbase + q * 32 + srow) * Dk + kOff);
#pragma unroll
        for (int q = 0; q < 2; ++q)
            bv[q] = *(const float4*)(sB + (size_t)(Nbase + q * 32 + srow) * Dk + kOff);
    };

    auto writeTiles = [&](int p, float scB) {
#pragma unroll
        for (int q = 0; q < 4; ++q) {
            bf16x4 v = { f2bf(av[q].x), f2bf(av[q].y), f2bf(av[q].z), f2bf(av[q].w) };
            *(bf16x4*)(&smA[p][swz(q * 32 + srow, scol * 2)]) = v;
        }
#pragma unroll
        for (int q = 0; q < 2; ++q) {
            bf16x4 v = { f2bf(bv[q].x * scB), f2bf(bv[q].y * scB),
                         f2bf(bv[q].z * scB), f2bf(bv[q].w * scB) };
            *(bf16x4*)(&smB[p][swz(q * 32 + srow, scol * 2)]) = v;
        }
    };

    // Prologue: stage tile 0, prefetch tile 1 into regs.
    loadTiles(0);
    writeTiles(0, W_S);
    loadTiles(1);
    __syncthreads();

    for (int kt = 0; kt < NKT; ++kt) {
        const int p = kt & 1;
        // Compute tile kt from buf p.
#pragma unroll
        for (int kk = 0; kk < 2; ++kk) {
            bf16x8 a[2], b[2];
            const int cb = kk * 64 + (lane >> 4) * 16;   // 16B-aligned col byte
#pragma unroll
            for (int m = 0; m < 2; ++m)
                a[m] = *(const bf16x8*)(&smA[p][swz(wr * 32 + m * 16 + (lane & 15), cb)]);
#pragma unroll
            for (int n = 0; n < 2; ++n)
                b[n] = *(const bf16x8*)(&smB[p][swz(wc * 32 + n * 16 + (lane & 15), cb)]);
#pragma unroll
            for (int m = 0; m < 2; ++m)
#pragma unroll
                for (int n = 0; n < 2; ++n)
                    acc[m][n] = __builtin_amdgcn_mfma_f32_16x16x32_bf16(a[m], b[n], acc[m][n], 0, 0, 0);
        }
        if (kt + 1 < NKT) {
            // buf p^1 last read at iter kt-1; that iter's barrier makes this safe.
            writeTiles(p ^ 1, (kt + 1 < 8) ? W_S : W_L);
            if (kt + 2 < NKT) loadTiles(kt + 2);
            __syncthreads();   // writes visible before iter kt+1 reads buf p^1
        }
    }

    // Epilogue: bias + store. D layout: col = lane&15, row = (lane>>4)*4 + r.
#pragma unroll
    for (int n = 0; n < 2; ++n) {
        const int j = Nbase + wc * 32 + n * 16 + (lane & 15);
        const float bias = W_S * bs[j] + W_L * bl[j];
#pragma unroll
        for (int m = 0; m < 2; ++m) {
            const int i0 = Mbase + wr * 32 + m * 16 + ((lane >> 4) << 2);
#pragma unroll
            for (int r = 0; r < 4; ++r)
                out[(size_t)(i0 + r) * Ndim + j] = acc[m][n][r] + bias;
        }
    }
}

extern "C" void kernel_launch(void* const* d_in, const int* in_sizes, int n_in,
                              void* d_out, int out_size, void* d_ws, size_t ws_size,
                              hipStream_t stream) {
    const float* S  = (const float*)d_in[0];   // small_graph_features [4096,512]
    const float* L  = (const float*)d_in[1];   // large_graph_features [4096,512]
    const float* Ws = (const float*)d_in[2];   // W_small [512,512]
    const float* bs = (const float*)d_in[3];   // b_small [512]
    const float* Wl = (const float*)d_in[4];   // W_large [512,512]
    const float* bl = (const float*)d_in[5];   // b_large [512]
    // d_in[6] = sigma: output does not depend on it (HSIC/MMD are dead code).

    const int grid = (Mdim / BM) * (Ndim / BN);   // 32*8 = 256
    fused_proj_kernel<<<grid, 512, 0, stream>>>(S, L, Ws, Wl, bs, bl, (float*)d_out);
}